// Round 1
// baseline (2345.689 us; speedup 1.0000x reference)
//
#include <hip/hip_runtime.h>

// BiLSTM-CRF on MI355X — round 1: correct end-to-end, fp32 compute, bf16 storage.
//
// Pipeline (5 launches on `stream`):
//   1. pack_whh    : Whh[1024x256] -> WhhT4[k][j] = float4(i,f,g,o rows)  (2 MiB)
//   2. gemm_x      : X4[d][t][b][j] = bf16x4( emb[sent] @ Wih^T + bih+bhh )  (64 MiB bf16)
//   3. lstm_scan   : 128 blocks = (dir, batch-row); h in LDS, c in regs; no cross-block sync
//   4. feats_kernel: feats[b][t][k] = [hf,hb] @ Wp^T + bp
//   5. viterbi     : per-b block, forward DP + in-LDS backpointers + backtrack
//
// ws layout: X4 (67108864 B) | WhhT4 (2097152 B) | H bf16 (16777216 B) | feats (786432 B)
// Output (float32): d_out[0:16384] = paths (as floats, -1 past length), d_out[16384:16448] = best_score.

#define NB 64
#define NT 256
#define NE 256
#define NHD 256
#define NKTAG 12
#define START_TAG 10

typedef unsigned short u16;

__device__ __forceinline__ float b2f(u16 u) {
  union { unsigned int i; float f; } v; v.i = ((unsigned int)u) << 16; return v.f;
}
__device__ __forceinline__ u16 f2b(float f) {
  union { float f; unsigned int i; } v; v.f = f;
  unsigned int r = v.i + 0x7FFFu + ((v.i >> 16) & 1u);
  return (u16)(r >> 16);
}
__device__ __forceinline__ float fsig(float x) { return 1.0f / (1.0f + __expf(-x)); }
__device__ __forceinline__ float ftanh(float x) { return 2.0f / (1.0f + __expf(-2.0f * x)) - 1.0f; }

// ---------------------------------------------------------------- pack_whh
// WhhT4[d][k][j] = float4(Whh_d[j][k], Whh_d[j+256][k], Whh_d[j+512][k], Whh_d[j+768][k])
__global__ __launch_bounds__(256) void pack_whh(const float* __restrict__ Whf,
                                                const float* __restrict__ Whb,
                                                float4* __restrict__ WT) {
  int gid = blockIdx.x * 256 + threadIdx.x;      // 2*256*256 = 131072
  int d = gid >> 16;
  int rem = gid & 65535;
  int k = rem >> 8, j = rem & 255;
  const float* W = d ? Whb : Whf;
  float4 o;
  o.x = W[(size_t)j * 256 + k];
  o.y = W[(size_t)(j + 256) * 256 + k];
  o.z = W[(size_t)(j + 512) * 256 + k];
  o.w = W[(size_t)(j + 768) * 256 + k];
  WT[gid] = o;
}

// ---------------------------------------------------------------- gemm_x
// C[i][n] = emb[sent[i]] @ W_all[n]^T + bias[n];  i=(b,t), n=(d,gate,j)
// 128(M) x 64(N) tile per 256-thread block; K=256 in 16-chunks.
__global__ __launch_bounds__(256) void gemm_x(const int* __restrict__ sent,
                                              const float* __restrict__ emb,
                                              const float* __restrict__ Wf,
                                              const float* __restrict__ Wb,
                                              const float* __restrict__ bihf,
                                              const float* __restrict__ bhhf,
                                              const float* __restrict__ bihb,
                                              const float* __restrict__ bhhb,
                                              u16* __restrict__ X4) {
  __shared__ float As[16][128];
  __shared__ float Bs[16][64];
  __shared__ int tok[128];
  int tid = threadIdx.x;
  int in = blockIdx.x;   // 0..31
  int im = blockIdx.y;   // 0..127
  if (tid < 128) tok[tid] = sent[im * 128 + tid];
  __syncthreads();
  float acc[8][4];
#pragma unroll
  for (int m = 0; m < 8; ++m)
#pragma unroll
    for (int n = 0; n < 4; ++n) acc[m][n] = 0.f;
  int ty = tid >> 4, tx = tid & 15;
  for (int kt = 0; kt < 16; ++kt) {
    int k0 = kt * 16;
#pragma unroll
    for (int l = 0; l < 2; ++l) {
      int idx = l * 256 + tid;
      int row = idx >> 2, kq = idx & 3;
      const float* ap = emb + (size_t)tok[row] * 256 + k0 + kq * 4;
      float4 av = *(const float4*)ap;
      As[kq * 4 + 0][row] = av.x; As[kq * 4 + 1][row] = av.y;
      As[kq * 4 + 2][row] = av.z; As[kq * 4 + 3][row] = av.w;
    }
    {
      int nrow = tid >> 2, kq = tid & 3;
      int ng = in * 64 + nrow;
      const float* wrow = (ng < 1024) ? (Wf + (size_t)ng * 256) : (Wb + (size_t)(ng - 1024) * 256);
      float4 bv = *(const float4*)(wrow + k0 + kq * 4);
      Bs[kq * 4 + 0][nrow] = bv.x; Bs[kq * 4 + 1][nrow] = bv.y;
      Bs[kq * 4 + 2][nrow] = bv.z; Bs[kq * 4 + 3][nrow] = bv.w;
    }
    __syncthreads();
#pragma unroll
    for (int k = 0; k < 16; ++k) {
      float4 a0 = *(const float4*)&As[k][ty * 8];
      float4 a1 = *(const float4*)&As[k][ty * 8 + 4];
      float4 bb = *(const float4*)&Bs[k][tx * 4];
      float am[8] = {a0.x, a0.y, a0.z, a0.w, a1.x, a1.y, a1.z, a1.w};
      float bn[4] = {bb.x, bb.y, bb.z, bb.w};
#pragma unroll
      for (int m = 0; m < 8; ++m)
#pragma unroll
        for (int n = 0; n < 4; ++n) acc[m][n] += am[m] * bn[n];
    }
    __syncthreads();
  }
  // epilogue: scatter into X4[d][t][b][j][gate] as bf16, bias folded (bih+bhh)
#pragma unroll
  for (int n = 0; n < 4; ++n) {
    int ng = in * 64 + tx * 4 + n;
    int d = ng >> 10, r = ng & 1023;
    int g = r >> 8, j = r & 255;
    float bias = d ? (bihb[r] + bhhb[r]) : (bihf[r] + bhhf[r]);
#pragma unroll
    for (int m = 0; m < 8; ++m) {
      int i = im * 128 + ty * 8 + m;
      int bb_ = i >> 8, tt = i & 255;
      size_t o = ((((size_t)d * NT + tt) * NB + bb_) * 256 + j) * 4 + g;
      X4[o] = f2b(acc[m][n] + bias);
    }
  }
}

// ---------------------------------------------------------------- lstm_scan
// One block per (dir d, batch b). Thread j owns hidden unit j (c in reg),
// h lives in LDS. Per step: acc(ifgo) = X4 + sum_k WhhT4[k][j] * h[k].
__global__ __launch_bounds__(256) void lstm_scan(const float4* __restrict__ WT,
                                                 const ushort4* __restrict__ X4,
                                                 const float* __restrict__ h0,
                                                 const float* __restrict__ c0,
                                                 u16* __restrict__ H) {
  int d = blockIdx.x >> 6, b = blockIdx.x & 63;
  int j = threadIdx.x;
  __shared__ float h_lds[256];
  float c = c0[((size_t)d * NB + b) * 256 + j];
  h_lds[j] = h0[((size_t)d * NB + b) * 256 + j];
  const float4* W = WT + (size_t)d * 65536;  // [k][j]
  __syncthreads();
  for (int s = 0; s < NT; ++s) {
    int t = d ? (NT - 1 - s) : s;
    ushort4 xg = X4[(((size_t)d * NT + t) * NB + b) * 256 + j];
    float ai = b2f(xg.x), af = b2f(xg.y), ag = b2f(xg.z), ao = b2f(xg.w);
#pragma unroll 8
    for (int k = 0; k < 256; ++k) {
      float4 w = W[k * 256 + j];
      float hk = h_lds[k];
      ai += w.x * hk; af += w.y * hk; ag += w.z * hk; ao += w.w * hk;
    }
    float ii = fsig(ai), ff = fsig(af), gg = ftanh(ag), oo = fsig(ao);
    c = ff * c + ii * gg;
    float h = oo * ftanh(c);
    __syncthreads();          // all reads of h_lds for this step are done
    h_lds[j] = h;
    H[(((size_t)d * NB + b) * NT + t) * 256 + j] = f2b(h);
    __syncthreads();          // h_lds updated before next step reads
  }
}

// ---------------------------------------------------------------- feats
// feats[b][t][k] = sum_j hf*Wp[k][j] + hb*Wp[k][256+j] + bp[k]
__global__ __launch_bounds__(384) void feats_kernel(const u16* __restrict__ H,
                                                    const float* __restrict__ Wp,
                                                    const float* __restrict__ bp,
                                                    float* __restrict__ FT) {
  __shared__ float hbuf[32][516];
  int tid = threadIdx.x;
  int i0 = blockIdx.x * 32;
  for (int idx = tid; idx < 32 * 512; idx += 384) {
    int row = idx >> 9, col = idx & 511;
    int i = i0 + row;
    int b = i >> 8, t = i & 255;
    int d = col >> 8, jj = col & 255;
    hbuf[row][col] = b2f(H[(((size_t)d * NB + b) * NT + t) * 256 + jj]);
  }
  __syncthreads();
  int row = tid / 12, k = tid - row * 12;  // 384 = 32*12
  const float* wp = Wp + (size_t)k * 512;
  float s = 0.f;
  for (int ccol = 0; ccol < 512; ++ccol) s += hbuf[row][ccol] * wp[ccol];
  int i = i0 + row;
  FT[(size_t)i * NKTAG + k] = s + bp[k];
}

// ---------------------------------------------------------------- viterbi
// One block (1 wave) per batch row. Forward DP over T with backpointers in
// LDS, then serial backtrack on lane 0, parallel masked path write.
__global__ __launch_bounds__(64) void viterbi_kernel(const float* __restrict__ FT,
                                                     const float* __restrict__ trans,
                                                     const int* __restrict__ sent,
                                                     float* __restrict__ out) {
  int b = blockIdx.x, tid = threadIdx.x;
  __shared__ float trans_s[12][12];
  __shared__ float s_s[12];
  __shared__ unsigned char bp_s[256][12];
  __shared__ int path_s[256];
  for (int idx = tid; idx < 144; idx += 64) trans_s[idx / 12][idx % 12] = trans[idx];
  // lengths[b] = sum(sentence[b] > 0)
  int cnt = 0;
#pragma unroll
  for (int q = 0; q < 4; ++q) cnt += (sent[b * NT + q * 64 + tid] > 0) ? 1 : 0;
  for (int off = 32; off; off >>= 1) cnt += __shfl_down(cnt, off);
  int len = __shfl(cnt, 0);
  if (tid < 12) s_s[tid] = (tid == START_TAG) ? 0.f : -10000.f;
  __syncthreads();
  for (int t = 0; t < NT; ++t) {
    float best = 0.f, f = 0.f;
    int barg = 0;
    if (tid < 12) {
      f = FT[((size_t)b * NT + t) * NKTAG + tid];
      best = s_s[0] + trans_s[tid][0];
      barg = 0;
#pragma unroll
      for (int fr = 1; fr < 12; ++fr) {
        float v = s_s[fr] + trans_s[tid][fr];
        if (v > best) { best = v; barg = fr; }  // strict > keeps first (jnp.argmax)
      }
    }
    __syncthreads();
    if (tid < 12) {
      s_s[tid] = best + f;
      bp_s[t][tid] = (unsigned char)barg;
    }
    __syncthreads();
  }
  if (tid == 0) {
    float bs = s_s[0];
    int bt = 0;
    for (int k = 1; k < 12; ++k)
      if (s_s[k] > bs) { bs = s_s[k]; bt = k; }
    out[NB * NT + b] = bs;  // best_score
    int x = bt;
    for (int tt = NT - 1; tt >= 0; --tt) {
      path_s[tt] = x;                  // emit BEFORE stepping back (ref semantics)
      int nxt = bp_s[tt][x];
      if (tt < len) x = nxt;
    }
  }
  __syncthreads();
#pragma unroll
  for (int q = 0; q < 4; ++q) {
    int t = q * 64 + tid;
    out[b * NT + t] = (t < len) ? (float)path_s[t] : -1.0f;
  }
}

// ---------------------------------------------------------------- launch
extern "C" void kernel_launch(void* const* d_in, const int* in_sizes, int n_in,
                              void* d_out, int out_size, void* d_ws, size_t ws_size,
                              hipStream_t stream) {
  (void)in_sizes; (void)n_in; (void)out_size; (void)ws_size;
  const int*   sent  = (const int*)d_in[0];
  const float* emb   = (const float*)d_in[2];
  const float* Wih_f = (const float*)d_in[3];
  const float* Whh_f = (const float*)d_in[4];
  const float* bih_f = (const float*)d_in[5];
  const float* bhh_f = (const float*)d_in[6];
  const float* Wih_b = (const float*)d_in[7];
  const float* Whh_b = (const float*)d_in[8];
  const float* bih_b = (const float*)d_in[9];
  const float* bhh_b = (const float*)d_in[10];
  const float* Wp    = (const float*)d_in[11];
  const float* bp    = (const float*)d_in[12];
  const float* trans = (const float*)d_in[13];
  const float* h0    = (const float*)d_in[14];
  const float* c0    = (const float*)d_in[15];
  float* out = (float*)d_out;

  char* w = (char*)d_ws;
  u16*   X4 = (u16*)w;                                          // 67108864 B
  float* WT = (float*)(w + 67108864);                           //  2097152 B
  u16*   H  = (u16*)(w + 67108864 + 2097152);                   // 16777216 B
  float* FT = (float*)(w + 67108864 + 2097152 + 16777216);      //   786432 B

  pack_whh<<<dim3(512), dim3(256), 0, stream>>>(Whh_f, Whh_b, (float4*)WT);
  gemm_x<<<dim3(32, 128), dim3(256), 0, stream>>>(sent, emb, Wih_f, Wih_b,
                                                  bih_f, bhh_f, bih_b, bhh_b, X4);
  lstm_scan<<<dim3(128), dim3(256), 0, stream>>>((const float4*)WT, (const ushort4*)X4,
                                                 h0, c0, H);
  feats_kernel<<<dim3(512), dim3(384), 0, stream>>>(H, Wp, bp, FT);
  viterbi_kernel<<<dim3(64), dim3(64), 0, stream>>>(FT, trans, sent, out);
}